// Round 3
// baseline (73.415 us; speedup 1.0000x reference)
//
#include <hip/hip_runtime.h>
#include <hip/hip_bf16.h>

// B=1024, D=512, K=256, NC=1.
// out[b,k] = sum_d w[k,d]*x[b,d]^2 + a2[k,d]*x[b,d] + c[k]
//   w = 0.5*softplus(rho)^2, a2 = -2*w*m, c = sum_d w*m^2
// Single fused kernel: dual bf16 MFMA over D, on-the-fly conversion, no workspace.

#define BB 1024
#define DD 512
#define KK 256
#define DC 64                 // d-chunk per iteration
#define NCHUNK (DD / DC)      // 8
#define XSTR 72               // LDS row stride (bf16 elems): 2-way bank alias only

typedef __attribute__((ext_vector_type(8))) short bf16x8;
typedef __attribute__((ext_vector_type(4))) float f32x4;
typedef __attribute__((ext_vector_type(4))) unsigned short us4;

static __device__ inline unsigned short f2bf(float f) {
    __hip_bfloat16 h = __float2bfloat16(f);   // round-to-nearest-even
    return *reinterpret_cast<unsigned short*>(&h);
}

__global__ __launch_bounds__(256) void fused_kernel(const float* __restrict__ x,
                                                    const float* __restrict__ means,
                                                    const float* __restrict__ rho,
                                                    float* __restrict__ out) {
    __shared__ unsigned short xsq[64][XSTR];   // bf16(x^2), [b_local][d]
    __shared__ unsigned short xln[64][XSTR];   // bf16(x)
    __shared__ unsigned short wT[16][XSTR];    // bf16(w),  [k_local][d]
    __shared__ unsigned short aT[16][XSTR];    // bf16(a2)
    __shared__ float red[256];
    __shared__ float csh[16];

    const int t    = threadIdx.x;
    const int kb   = blockIdx.x & 15;
    const int bb   = blockIdx.x >> 4;
    const int k0   = kb * 16;
    const int b0   = bb * 64;
    const int lane = t & 63;
    const int wave = t >> 6;
    const int col  = lane & 15;
    const int quad = lane >> 4;

    const int wk  = t >> 4;       // W staging: k_local (0..15)
    const int wc4 = t & 15;       // W staging: float4 col index

    float4 xr[4];
    float4 mr, rr;

    // prefetch chunk 0
#pragma unroll
    for (int j = 0; j < 4; j++) {
        const int idx = j * 256 + t;
        const int row = idx >> 4, c4 = idx & 15;
        xr[j] = *(const float4*)&x[(b0 + row) * DD + c4 * 4];
    }
    mr = *(const float4*)&means[(k0 + wk) * DD + wc4 * 4];
    rr = *(const float4*)&rho  [(k0 + wk) * DD + wc4 * 4];

    f32x4 acc = {0.f, 0.f, 0.f, 0.f};
    float csum = 0.f;

    for (int ic = 0; ic < NCHUNK; ic++) {
        // ---- convert + stage chunk ic into LDS ----
#pragma unroll
        for (int j = 0; j < 4; j++) {
            const int idx = j * 256 + t;
            const int row = idx >> 4, c4 = idx & 15;
            const float4 v = xr[j];
            us4 sq, ln;
            sq.x = f2bf(v.x * v.x); sq.y = f2bf(v.y * v.y);
            sq.z = f2bf(v.z * v.z); sq.w = f2bf(v.w * v.w);
            ln.x = f2bf(v.x); ln.y = f2bf(v.y); ln.z = f2bf(v.z); ln.w = f2bf(v.w);
            *(us4*)&xsq[row][c4 * 4] = sq;
            *(us4*)&xln[row][c4 * 4] = ln;
        }
        {
            us4 wq, aq;
            float sp, wv;
            sp = log1pf(expf(rr.x)); wv = 0.5f * sp * sp;
            wq.x = f2bf(wv); aq.x = f2bf(-2.f * wv * mr.x); csum += wv * mr.x * mr.x;
            sp = log1pf(expf(rr.y)); wv = 0.5f * sp * sp;
            wq.y = f2bf(wv); aq.y = f2bf(-2.f * wv * mr.y); csum += wv * mr.y * mr.y;
            sp = log1pf(expf(rr.z)); wv = 0.5f * sp * sp;
            wq.z = f2bf(wv); aq.z = f2bf(-2.f * wv * mr.z); csum += wv * mr.z * mr.z;
            sp = log1pf(expf(rr.w)); wv = 0.5f * sp * sp;
            wq.w = f2bf(wv); aq.w = f2bf(-2.f * wv * mr.w); csum += wv * mr.w * mr.w;
            *(us4*)&wT[wk][wc4 * 4] = wq;
            *(us4*)&aT[wk][wc4 * 4] = aq;
        }
        __syncthreads();

        // ---- prefetch chunk ic+1 (overlaps with MFMA below) ----
        if (ic + 1 < NCHUNK) {
            const int d0 = (ic + 1) * DC;
#pragma unroll
            for (int j = 0; j < 4; j++) {
                const int idx = j * 256 + t;
                const int row = idx >> 4, c4 = idx & 15;
                xr[j] = *(const float4*)&x[(b0 + row) * DD + d0 + c4 * 4];
            }
            mr = *(const float4*)&means[(k0 + wk) * DD + d0 + wc4 * 4];
            rr = *(const float4*)&rho  [(k0 + wk) * DD + d0 + wc4 * 4];
        }

        // ---- MFMA on chunk ic ----
#pragma unroll
        for (int dk = 0; dk < DC; dk += 32) {
            const bf16x8 a_sq = *(const bf16x8*)&xsq[wave * 16 + col][dk + quad * 8];
            const bf16x8 a_ln = *(const bf16x8*)&xln[wave * 16 + col][dk + quad * 8];
            const bf16x8 b_w  = *(const bf16x8*)&wT[col][dk + quad * 8];
            const bf16x8 b_a  = *(const bf16x8*)&aT[col][dk + quad * 8];
            acc = __builtin_amdgcn_mfma_f32_16x16x32_bf16(a_sq, b_w, acc, 0, 0, 0);
            acc = __builtin_amdgcn_mfma_f32_16x16x32_bf16(a_ln, b_a, acc, 0, 0, 0);
        }
        __syncthreads();
    }

    // ---- c[k] block reduction ----
    red[t] = csum;
    __syncthreads();
    if (t < 16) {
        float s = 0.f;
#pragma unroll
        for (int j = 0; j < 16; j++) s += red[t * 16 + j];
        csh[t] = s;
    }
    __syncthreads();

    const float cv = csh[col];
#pragma unroll
    for (int r = 0; r < 4; r++) {
        out[(b0 + wave * 16 + quad * 4 + r) * KK + (k0 + col)] = acc[r] + cv;
    }
}

extern "C" void kernel_launch(void* const* d_in, const int* in_sizes, int n_in,
                              void* d_out, int out_size, void* d_ws, size_t ws_size,
                              hipStream_t stream) {
    const float* x     = (const float*)d_in[0];
    const float* means = (const float*)d_in[1];
    const float* rho   = (const float*)d_in[2];
    float* out = (float*)d_out;

    fused_kernel<<<256, 256, 0, stream>>>(x, means, rho, out);
}

// Round 4
// 68.908 us; speedup vs baseline: 1.0654x; 1.0654x over previous
//
#include <hip/hip_runtime.h>
#include <hip/hip_bf16.h>

// B=1024, D=512, K=256, NC=1.
// out[b,k] = sum_d (x-m)^2 * 0.5*softplus(rho)^2
//          = sum_d w*x^2 + a2*x + c[k],  w=0.5*sp^2, a2=-2*w*m, c=sum_d w*m^2
// => GEMM: out = X' W'^T + c, X'=[x^2,x] (B x 1024 bf16), W'=[w,a2] (K x 1024 bf16)
// 2 dispatches: fused prep (X' + W' + c), then MFMA GEMM. Workspace: 2.5 MB (L2-resident).

#define BB 1024
#define DD 512
#define DP 1024
#define KK 256
#define PREP_X_BLOCKS 512   // (1024*512/4)/256
#define PREP_W_BLOCKS 128   // 2 k-rows per block

typedef __attribute__((ext_vector_type(8))) short bf16x8;
typedef __attribute__((ext_vector_type(4))) float f32x4;
typedef __attribute__((ext_vector_type(4))) unsigned short us4;

static __device__ inline unsigned short f2bf(float f) {
    __hip_bfloat16 h = __float2bfloat16(f);
    return *reinterpret_cast<unsigned short*>(&h);
}

__global__ __launch_bounds__(256) void prep_kernel(const float* __restrict__ x,
                                                   const float* __restrict__ means,
                                                   const float* __restrict__ rho,
                                                   unsigned short* __restrict__ Xp,
                                                   unsigned short* __restrict__ Wp,
                                                   float* __restrict__ c) {
    const int t = threadIdx.x;
    if (blockIdx.x < PREP_X_BLOCKS) {
        // ---- X' ----
        const int i = blockIdx.x * 256 + t;
        const int b  = i >> 7;
        const int d4 = (i & 127) * 4;
        const float4 xv = *(const float4*)&x[b * DD + d4];
        us4 sq, ln;
        sq.x = f2bf(xv.x * xv.x); sq.y = f2bf(xv.y * xv.y);
        sq.z = f2bf(xv.z * xv.z); sq.w = f2bf(xv.w * xv.w);
        ln.x = f2bf(xv.x); ln.y = f2bf(xv.y); ln.z = f2bf(xv.z); ln.w = f2bf(xv.w);
        *(us4*)&Xp[b * DP + d4]      = sq;
        *(us4*)&Xp[b * DP + DD + d4] = ln;
    } else {
        // ---- W' + c: 2 k-rows per block, 128 threads each ----
        __shared__ float red[256];
        const int blk  = blockIdx.x - PREP_X_BLOCKS;
        const int half = t >> 7;             // 0/1
        const int k    = blk * 2 + half;
        const int d4   = (t & 127) * 4;
        const float4 mv = *(const float4*)&means[k * DD + d4];
        const float4 rv = *(const float4*)&rho  [k * DD + d4];
        us4 wq, aq;
        float sp, wv, csum = 0.f;
        sp = log1pf(expf(rv.x)); wv = 0.5f * sp * sp;
        wq.x = f2bf(wv); aq.x = f2bf(-2.f * wv * mv.x); csum += wv * mv.x * mv.x;
        sp = log1pf(expf(rv.y)); wv = 0.5f * sp * sp;
        wq.y = f2bf(wv); aq.y = f2bf(-2.f * wv * mv.y); csum += wv * mv.y * mv.y;
        sp = log1pf(expf(rv.z)); wv = 0.5f * sp * sp;
        wq.z = f2bf(wv); aq.z = f2bf(-2.f * wv * mv.z); csum += wv * mv.z * mv.z;
        sp = log1pf(expf(rv.w)); wv = 0.5f * sp * sp;
        wq.w = f2bf(wv); aq.w = f2bf(-2.f * wv * mv.w); csum += wv * mv.w * mv.w;
        *(us4*)&Wp[k * DP + d4]      = wq;
        *(us4*)&Wp[k * DP + DD + d4] = aq;
        red[t] = csum;
        __syncthreads();
        if (t < 2) {
            float s = 0.f;
#pragma unroll
            for (int j = 0; j < 128; j++) s += red[t * 128 + j];
            c[blk * 2 + t] = s;
        }
    }
}

// 1024 wave-tiles (16x16) = 256 blocks x 4 waves; K-loop over DP=1024.
__global__ __launch_bounds__(256) void gemm_kernel(const unsigned short* __restrict__ Xp,
                                                   const unsigned short* __restrict__ Wp,
                                                   const float* __restrict__ c,
                                                   float* __restrict__ out) {
    const int lane = threadIdx.x & 63;
    const int wave = threadIdx.x >> 6;
    const int tile = blockIdx.x * 4 + wave;   // 0..1023
    const int kb = tile & 15;
    const int bb = tile >> 4;
    const int k0 = kb * 16;
    const int b0 = bb * 16;

    const int rc   = lane & 15;
    const int quad = lane >> 4;

    const unsigned short* aRow = Xp + (b0 + rc) * DP + quad * 8;
    const unsigned short* bRow = Wp + (k0 + rc) * DP + quad * 8;

    f32x4 acc = {0.f, 0.f, 0.f, 0.f};
#pragma unroll 8
    for (int dk = 0; dk < DP; dk += 32) {
        const bf16x8 a = *(const bf16x8*)(aRow + dk);
        const bf16x8 b = *(const bf16x8*)(bRow + dk);
        acc = __builtin_amdgcn_mfma_f32_16x16x32_bf16(a, b, acc, 0, 0, 0);
    }

    const float cv = c[k0 + rc];
#pragma unroll
    for (int r = 0; r < 4; r++) {
        out[(b0 + quad * 4 + r) * KK + (k0 + rc)] = acc[r] + cv;
    }
}

extern "C" void kernel_launch(void* const* d_in, const int* in_sizes, int n_in,
                              void* d_out, int out_size, void* d_ws, size_t ws_size,
                              hipStream_t stream) {
    const float* x     = (const float*)d_in[0];
    const float* means = (const float*)d_in[1];
    const float* rho   = (const float*)d_in[2];
    float* out = (float*)d_out;

    unsigned short* Xp = (unsigned short*)d_ws;         // 2 MB
    unsigned short* Wp = Xp + (size_t)BB * DP;          // 512 KB
    float* c = (float*)(Wp + (size_t)KK * DP);          // 1 KB

    prep_kernel<<<PREP_X_BLOCKS + PREP_W_BLOCKS, 256, 0, stream>>>(x, means, rho, Xp, Wp, c);
    gemm_kernel<<<256, 256, 0, stream>>>(Xp, Wp, c, out);
}